// Round 6
// baseline (492.498 us; speedup 1.0000x reference)
//
#include <hip/hip_runtime.h>

// Problem: B=2, C=6 (DTI lower-tri), H=W=D=64. fp32 in, fp32 out.
// out[b,c,x,y,z] = (R^T M R)[I[c],J[c]]
//   M = 3x3 symmetric from trilinear-warped DTI (border clamp, align_corners)
//   R = orthogonal polar factor of J = I + du/dx  (== U @ Vh of SVD(J))
//
// R11: single fused kernel, NO workspace. Evidence ledger:
//   - ~85 us/iter of unconditional 256 MiB d_ws poison fills (harness floor).
//   - Dirtying d_ws costs ~4-5 us extra (R0/R3/R5 all 105.7-108.1 vs
//     R1's no-write 102.2) -> never write d_ws.
//   - R4's fused attempt died from __launch_bounds__(256,8): the VGPR cap
//     (32) spilled the HOT path (449 us). The cap was the bug, not fusion.
// This version: plain __launch_bounds__(256); rare fp64 rescue (~50 of
// 524288 threads, cond(J)>1e4) inline behind a branch with ALL its arrays
// volatile -> scratch, so the cold branch's register demand (~30 VGPR)
// stays under the hot path's ~50 and can't raise the kernel's static VGPR
// allocation. Scratch traffic: 216 B x ~50 threads = negligible.
// Go/no-go signal in counters: VGPR_Count ~48-64 good; ~32 means the trap
// re-sprung.
#define NVOX 262144          // 64^3
#define TOTAL (2 * NVOX)     // B * H * W * D threads

typedef float f2u __attribute__((ext_vector_type(2), aligned(4)));

__global__ __launch_bounds__(256)
void warp_fused(const float* __restrict__ dti,
                const float* __restrict__ ddf,
                float* __restrict__ out)
{
    const int idx = blockIdx.x * 256 + threadIdx.x;   // exactly TOTAL threads
    const int b = idx >> 18;
    const int r = idx & (NVOX - 1);
    const int x = r >> 12;
    const int y = (r >> 6) & 63;
    const int z = r & 63;              // == lane (wave spans z row; y,x fixed)

    const float* db = ddf + (size_t)b * 3 * NVOX;

    // ---------------- displacement at center ----------------
    const float ux = db[r];
    const float uy = db[NVOX + r];
    const float uz = db[2 * NVOX + r];

    // ---------------- trilinear warp, border padding ----------------
    const float cx = fminf(fmaxf((float)x + ux, 0.0f), 63.0f);
    const float cy = fminf(fmaxf((float)y + uy, 0.0f), 63.0f);
    const float cz = fminf(fmaxf((float)z + uz, 0.0f), 63.0f);
    const float fx0 = floorf(cx), fy0 = floorf(cy), fz0 = floorf(cz);
    const float fx = cx - fx0, fy = cy - fy0, fz = cz - fz0;
    const int x0 = (int)fx0, y0 = (int)fy0, z0 = (int)fz0;
    const int x1 = min(x0 + 1, 63), y1 = min(y0 + 1, 63);

    const float gx = 1.0f - fx, gy = 1.0f - fy, gz = 1.0f - fz;
    const float q00 = gx * gy, q01 = gx * fy, q10 = fx * gy, q11 = fx * fy;

    // z0/z1 adjacent -> one 8B load per (x,y) corner per channel (24 vs 48).
    // z0==63 (only when cz==63.0, fz=0): shift base to 62, take .y for z0.
    const bool ztop = (z0 == 63);
    const int zb = ztop ? 62 : z0;
    const int p00 = (x0 * 64 + y0) * 64 + zb, p01 = (x0 * 64 + y1) * 64 + zb;
    const int p10 = (x1 * 64 + y0) * 64 + zb, p11 = (x1 * 64 + y1) * 64 + zb;

    const float* tb = dti + (size_t)b * 6 * NVOX;
    float m[6];
#pragma unroll
    for (int c = 0; c < 6; ++c) {
        const float* tc = tb + c * NVOX;
        const f2u v00 = *(const f2u*)(tc + p00);
        const f2u v01 = *(const f2u*)(tc + p01);
        const f2u v10 = *(const f2u*)(tc + p10);
        const f2u v11 = *(const f2u*)(tc + p11);
        const float l00 = (ztop ? v00.y : v00.x) * gz + v00.y * fz;
        const float l01 = (ztop ? v01.y : v01.x) * gz + v01.y * fz;
        const float l10 = (ztop ? v10.y : v10.x) * gz + v10.y * fz;
        const float l11 = (ztop ? v11.y : v11.x) * gz + v11.y * fz;
        m[c] = q00 * l00 + q01 * l01 + q10 * l10 + q11 * l11;
    }

    // -------- Jacobian J = I + du/dx (np.gradient semantics), fp32 ---------
    const int xm = max(x - 1, 0), xp = min(x + 1, 63);
    const int ym = max(y - 1, 0), yp = min(y + 1, 63);
    const int zm = max(z - 1, 0), zp = min(z + 1, 63);
    const float sx = (xp - xm == 2) ? 0.5f : 1.0f;
    const float sy = (yp - ym == 2) ? 0.5f : 1.0f;
    const float sz = (zp - zm == 2) ? 0.5f : 1.0f;

    float P[3][3];
#pragma unroll
    for (int i = 0; i < 3; ++i) {
        const float* ui = db + i * NVOX;
        const float ctr = (i == 0) ? ux : (i == 1) ? uy : uz;
        P[i][0] = (ui[(xp * 64 + y) * 64 + z] - ui[(xm * 64 + y) * 64 + z]) * sx
                + (i == 0 ? 1.0f : 0.0f);
        P[i][1] = (ui[(x * 64 + yp) * 64 + z] - ui[(x * 64 + ym) * 64 + z]) * sy
                + (i == 1 ? 1.0f : 0.0f);
        // z-row lives in this wave: lane == z
        P[i][2] = (__shfl(ctr, zp) - __shfl(ctr, zm)) * sz + (i == 2 ? 1.0f : 0.0f);
    }

    // -------- fp32 scaled-Newton polar, 6 iters (enough for cond <= 1e4) ----
    // P <- c1*P + c2*cof(P); with t = ||cof||_F/||P||_F, ad = |det|:
    //   c1 = 0.5*sqrt(t/ad) = 0.5*t*rsq(t*ad),  c2 = 0.5*sgn(det)*rsq(t*ad).
    // HW v_rcp/v_rsq/v_sqrt: scaled-Newton is invariant to small scaling
    // error (only perturbs acceleration, not the orthogonal limit).
    bool need64 = false;
#pragma unroll
    for (int it = 0; it < 6; ++it) {
        const float C00 = P[1][1] * P[2][2] - P[1][2] * P[2][1];
        const float C01 = P[1][2] * P[2][0] - P[1][0] * P[2][2];
        const float C02 = P[1][0] * P[2][1] - P[1][1] * P[2][0];
        const float C10 = P[0][2] * P[2][1] - P[0][1] * P[2][2];
        const float C11 = P[0][0] * P[2][2] - P[0][2] * P[2][0];
        const float C12 = P[0][1] * P[2][0] - P[0][0] * P[2][1];
        const float C20 = P[0][1] * P[1][2] - P[0][2] * P[1][1];
        const float C21 = P[0][2] * P[1][0] - P[0][0] * P[1][2];
        const float C22 = P[0][0] * P[1][1] - P[0][1] * P[1][0];
        const float det = P[0][0] * C00 + P[0][1] * C01 + P[0][2] * C02;

        const float n2 = P[0][0]*P[0][0] + P[0][1]*P[0][1] + P[0][2]*P[0][2]
                       + P[1][0]*P[1][0] + P[1][1]*P[1][1] + P[1][2]*P[1][2]
                       + P[2][0]*P[2][0] + P[2][1]*P[2][1] + P[2][2]*P[2][2];
        const float a2 = C00*C00 + C01*C01 + C02*C02
                       + C10*C10 + C11*C11 + C12*C12
                       + C20*C20 + C21*C21 + C22*C22;

        const float ad = fmaxf(fabsf(det), 1e-30f);
        // cond_est = sqrt(n2*a2)/ad > 1e4  <=>  n2*a2 > 1e8*ad^2 (no sqrt)
        if (it == 0) need64 = (n2 * a2 > 1e8f * ad * ad);

        const float t  = fmaxf(__builtin_amdgcn_sqrtf(a2 * __builtin_amdgcn_rcpf(n2)), 1e-20f);
        const float sg = (det < 0.0f) ? -1.0f : 1.0f;
        const float rt = __builtin_amdgcn_rsqf(t * ad);   // 1/sqrt(t*ad)
        const float c1 = 0.5f * t * rt;                   // 0.5*sqrt(t/ad)
        const float c2 = 0.5f * sg * rt;

        P[0][0] = c1 * P[0][0] + c2 * C00;  P[0][1] = c1 * P[0][1] + c2 * C01;  P[0][2] = c1 * P[0][2] + c2 * C02;
        P[1][0] = c1 * P[1][0] + c2 * C10;  P[1][1] = c1 * P[1][1] + c2 * C11;  P[1][2] = c1 * P[1][2] + c2 * C12;
        P[2][0] = c1 * P[2][0] + c2 * C20;  P[2][1] = c1 * P[2][1] + c2 * C21;  P[2][2] = c1 * P[2][2] + c2 * C22;
    }

    // ---------------- A = R^T * M * R (fp32 fast path) ----------------
    const float M3[3][3] = {{m[0], m[1], m[3]},
                            {m[1], m[2], m[4]},
                            {m[3], m[4], m[5]}};
    float T[3][3];
#pragma unroll
    for (int i = 0; i < 3; ++i)
#pragma unroll
        for (int j = 0; j < 3; ++j)
            T[i][j] = P[0][i] * M3[0][j] + P[1][i] * M3[1][j] + P[2][i] * M3[2][j];

    float A[3][3];
#pragma unroll
    for (int i = 0; i < 3; ++i)
#pragma unroll
        for (int j = 0; j < 3; ++j)
            A[i][j] = T[i][0] * P[0][j] + T[i][1] * P[1][j] + T[i][2] * P[2][j];

    // ---------------- emit lower-tri (B,6,H,W,D) fp32 ----------------
    float* ob = out + (size_t)b * 6 * NVOX;
    ob[0 * NVOX + r] = A[0][0];
    ob[1 * NVOX + r] = A[1][0];
    ob[2 * NVOX + r] = A[1][1];
    ob[3 * NVOX + r] = A[2][0];
    ob[4 * NVOX + r] = A[2][1];
    ob[5 * NVOX + r] = A[2][2];

    // -------- inline fp64 rescue, ~1e-4 of threads (cond(J) > 1e4) ---------
    // ALL arrays volatile -> scratch, keeping the cold branch's register
    // demand below the hot path's (~50 VGPR). No launch-bounds cap (R4's
    // bug). Divergence/scratch latency irrelevant at this rarity.
    if (__builtin_expect(need64, 0)) {
        volatile double X[9];
        for (int i = 0; i < 3; ++i) {
            const float* u = db + i * NVOX;
            const double dgx = ((double)u[(xp*64+y)*64+z] - (double)u[(xm*64+y)*64+z])
                             * ((xp - xm == 2) ? 0.5 : 1.0);
            const double dgy = ((double)u[(x*64+yp)*64+z] - (double)u[(x*64+ym)*64+z])
                             * ((yp - ym == 2) ? 0.5 : 1.0);
            const double dgz = ((double)u[(x*64+y)*64+zp] - (double)u[(x*64+y)*64+zm])
                             * ((zp - zm == 2) ? 0.5 : 1.0);
            X[i*3+0] = dgx + (i == 0 ? 1.0 : 0.0);
            X[i*3+1] = dgy + (i == 1 ? 1.0 : 0.0);
            X[i*3+2] = dgz + (i == 2 ? 1.0 : 0.0);
        }

        volatile double C[9];
        for (int it = 0; it < 14; ++it) {   // normalized Newton, overflow-proof
            double mx = 0.0;
            for (int k = 0; k < 9; ++k) mx = fmax(mx, fabs(X[k]));
            const double s = 1.0 / fmax(mx, 1e-300);
            for (int k = 0; k < 9; ++k) X[k] = X[k] * s;

            C[0] = X[4]*X[8] - X[5]*X[7];
            C[1] = X[5]*X[6] - X[3]*X[8];
            C[2] = X[3]*X[7] - X[4]*X[6];
            C[3] = X[2]*X[7] - X[1]*X[8];
            C[4] = X[0]*X[8] - X[2]*X[6];
            C[5] = X[1]*X[6] - X[0]*X[7];
            C[6] = X[1]*X[5] - X[2]*X[4];
            C[7] = X[2]*X[3] - X[0]*X[5];
            C[8] = X[0]*X[4] - X[1]*X[3];
            const double det = X[0]*C[0] + X[1]*C[1] + X[2]*C[2];
            double n2d = 0.0, a2d = 0.0;
            for (int k = 0; k < 9; ++k) { n2d += X[k]*X[k]; a2d += C[k]*C[k]; }
            const double t  = fmax(sqrt(a2d / n2d), 1e-150);
            const double ad = fmax(fabs(det), 1e-280);
            const double sg = (det < 0.0) ? -1.0 : 1.0;
            const double c1 = 0.5 * sqrt(t / ad);
            const double c2 = 0.5 * sg / sqrt(t * ad);
            for (int k = 0; k < 9; ++k) X[k] = c1 * X[k] + c2 * C[k];
        }

        // A = X^T * M * X  (X is now R; reuse fp32 m[] — M is well-conditioned)
        volatile double Md[9];
        Md[0] = m[0]; Md[1] = m[1]; Md[2] = m[3];
        Md[3] = m[1]; Md[4] = m[2]; Md[5] = m[4];
        Md[6] = m[3]; Md[7] = m[4]; Md[8] = m[5];
        volatile double Td[9];
        for (int i = 0; i < 3; ++i)
            for (int j = 0; j < 3; ++j)
                Td[i*3+j] = X[0+i]*Md[0+j] + X[3+i]*Md[3+j] + X[6+i]*Md[6+j];

        ob[0 * NVOX + r] = (float)(Td[0]*X[0] + Td[1]*X[3] + Td[2]*X[6]);  // A00
        ob[1 * NVOX + r] = (float)(Td[3]*X[0] + Td[4]*X[3] + Td[5]*X[6]);  // A10
        ob[2 * NVOX + r] = (float)(Td[3]*X[1] + Td[4]*X[4] + Td[5]*X[7]);  // A11
        ob[3 * NVOX + r] = (float)(Td[6]*X[0] + Td[7]*X[3] + Td[8]*X[6]);  // A20
        ob[4 * NVOX + r] = (float)(Td[6]*X[1] + Td[7]*X[4] + Td[8]*X[7]);  // A21
        ob[5 * NVOX + r] = (float)(Td[6]*X[2] + Td[7]*X[5] + Td[8]*X[8]);  // A22
    }
}

extern "C" void kernel_launch(void* const* d_in, const int* in_sizes, int n_in,
                              void* d_out, int out_size, void* d_ws, size_t ws_size,
                              hipStream_t stream) {
    const float* dti = (const float*)d_in[0];
    const float* ddf = (const float*)d_in[1];
    float* out = (float*)d_out;
    (void)d_ws; (void)ws_size;   // NEVER touch d_ws: dirtying it costs ~5 us

    warp_fused<<<TOTAL / 256, 256, 0, stream>>>(dti, ddf, out);
}

// Round 7
// 94.174 us; speedup vs baseline: 5.2297x; 5.2297x over previous
//
#include <hip/hip_runtime.h>

// Problem: B=2, C=6 (DTI lower-tri), H=W=D=64. fp32 in, fp32 out.
// out[b,c,x,y,z] = (R^T M R)[I[c],J[c]]
//   M = 3x3 symmetric from trilinear-warped DTI (border clamp, align_corners)
//   R = orthogonal polar factor of J = I + du/dx  (== U @ Vh of SVD(J))
//
// R12: single fused kernel, rescue state in LDS. Evidence ledger:
//   - ~85 us/iter unconditional 256 MiB d_ws poison fills (harness floor).
//   - Dirtying d_ws costs ~4-5 us (R0/R3/R5 vs R1) -> never write d_ws.
//   - ANY per-thread scratch allocation collapses occupancy to ~0.3-3% and
//     runs ~450-490 us (R4: VGPR-capped spill; R11: volatile cold-branch
//     arrays; same failure with VGPR=32 and VGPR=56) -> ScratchSize MUST be 0.
//   - fp64 state in VGPRs raises kernel VGPR to ~92 -> occupancy cliff
//     (historical 57 us warp_main).
// => the rescue state lives in LDS: one 144 B slot per wave (X[9]+C[9]
// doubles, 4 waves -> 1152 B/block, no occupancy impact). Flagged lanes
// (~50 of 524288, cond(J)>1e4) are serialized within their wave via
// ballot+ffs loop, each using the wave's slot. Cold-branch register
// demand ~30 < hot path ~56, so static VGPR stays at the hot path's.
#define NVOX 262144          // 64^3
#define TOTAL (2 * NVOX)     // B * H * W * D threads

typedef float f2u __attribute__((ext_vector_type(2), aligned(4)));

__global__ __launch_bounds__(256)
void warp_fused(const float* __restrict__ dti,
                const float* __restrict__ ddf,
                float* __restrict__ out)
{
    __shared__ double sX[4][9];   // per-wave fp64 rescue state (LDS, not scratch)
    __shared__ double sC[4][9];

    const int idx = blockIdx.x * 256 + threadIdx.x;   // exactly TOTAL threads
    const int b = idx >> 18;
    const int r = idx & (NVOX - 1);
    const int x = r >> 12;
    const int y = (r >> 6) & 63;
    const int z = r & 63;              // == lane (wave spans z row; y,x fixed)

    const float* db = ddf + (size_t)b * 3 * NVOX;

    // ---------------- displacement at center ----------------
    const float ux = db[r];
    const float uy = db[NVOX + r];
    const float uz = db[2 * NVOX + r];

    // ---------------- trilinear warp, border padding ----------------
    const float cx = fminf(fmaxf((float)x + ux, 0.0f), 63.0f);
    const float cy = fminf(fmaxf((float)y + uy, 0.0f), 63.0f);
    const float cz = fminf(fmaxf((float)z + uz, 0.0f), 63.0f);
    const float fx0 = floorf(cx), fy0 = floorf(cy), fz0 = floorf(cz);
    const float fx = cx - fx0, fy = cy - fy0, fz = cz - fz0;
    const int x0 = (int)fx0, y0 = (int)fy0, z0 = (int)fz0;
    const int x1 = min(x0 + 1, 63), y1 = min(y0 + 1, 63);

    const float gx = 1.0f - fx, gy = 1.0f - fy, gz = 1.0f - fz;
    const float q00 = gx * gy, q01 = gx * fy, q10 = fx * gy, q11 = fx * fy;

    // z0/z1 adjacent -> one 8B load per (x,y) corner per channel (24 vs 48).
    // z0==63 (only when cz==63.0, fz=0): shift base to 62, take .y for z0.
    const bool ztop = (z0 == 63);
    const int zb = ztop ? 62 : z0;
    const int p00 = (x0 * 64 + y0) * 64 + zb, p01 = (x0 * 64 + y1) * 64 + zb;
    const int p10 = (x1 * 64 + y0) * 64 + zb, p11 = (x1 * 64 + y1) * 64 + zb;

    const float* tb = dti + (size_t)b * 6 * NVOX;
    float m[6];
#pragma unroll
    for (int c = 0; c < 6; ++c) {
        const float* tc = tb + c * NVOX;
        const f2u v00 = *(const f2u*)(tc + p00);
        const f2u v01 = *(const f2u*)(tc + p01);
        const f2u v10 = *(const f2u*)(tc + p10);
        const f2u v11 = *(const f2u*)(tc + p11);
        const float l00 = (ztop ? v00.y : v00.x) * gz + v00.y * fz;
        const float l01 = (ztop ? v01.y : v01.x) * gz + v01.y * fz;
        const float l10 = (ztop ? v10.y : v10.x) * gz + v10.y * fz;
        const float l11 = (ztop ? v11.y : v11.x) * gz + v11.y * fz;
        m[c] = q00 * l00 + q01 * l01 + q10 * l10 + q11 * l11;
    }

    // -------- Jacobian J = I + du/dx (np.gradient semantics), fp32 ---------
    const int xm = max(x - 1, 0), xp = min(x + 1, 63);
    const int ym = max(y - 1, 0), yp = min(y + 1, 63);
    const int zm = max(z - 1, 0), zp = min(z + 1, 63);
    const float sx = (xp - xm == 2) ? 0.5f : 1.0f;
    const float sy = (yp - ym == 2) ? 0.5f : 1.0f;
    const float sz = (zp - zm == 2) ? 0.5f : 1.0f;

    float P[3][3];
#pragma unroll
    for (int i = 0; i < 3; ++i) {
        const float* ui = db + i * NVOX;
        const float ctr = (i == 0) ? ux : (i == 1) ? uy : uz;
        P[i][0] = (ui[(xp * 64 + y) * 64 + z] - ui[(xm * 64 + y) * 64 + z]) * sx
                + (i == 0 ? 1.0f : 0.0f);
        P[i][1] = (ui[(x * 64 + yp) * 64 + z] - ui[(x * 64 + ym) * 64 + z]) * sy
                + (i == 1 ? 1.0f : 0.0f);
        // z-row lives in this wave: lane == z
        P[i][2] = (__shfl(ctr, zp) - __shfl(ctr, zm)) * sz + (i == 2 ? 1.0f : 0.0f);
    }

    // -------- fp32 scaled-Newton polar, 6 iters (enough for cond <= 1e4) ----
    // P <- c1*P + c2*cof(P); with t = ||cof||_F/||P||_F, ad = |det|:
    //   c1 = 0.5*sqrt(t/ad) = 0.5*t*rsq(t*ad),  c2 = 0.5*sgn(det)*rsq(t*ad).
    bool need64 = false;
#pragma unroll
    for (int it = 0; it < 6; ++it) {
        const float C00 = P[1][1] * P[2][2] - P[1][2] * P[2][1];
        const float C01 = P[1][2] * P[2][0] - P[1][0] * P[2][2];
        const float C02 = P[1][0] * P[2][1] - P[1][1] * P[2][0];
        const float C10 = P[0][2] * P[2][1] - P[0][1] * P[2][2];
        const float C11 = P[0][0] * P[2][2] - P[0][2] * P[2][0];
        const float C12 = P[0][1] * P[2][0] - P[0][0] * P[2][1];
        const float C20 = P[0][1] * P[1][2] - P[0][2] * P[1][1];
        const float C21 = P[0][2] * P[1][0] - P[0][0] * P[1][2];
        const float C22 = P[0][0] * P[1][1] - P[0][1] * P[1][0];
        const float det = P[0][0] * C00 + P[0][1] * C01 + P[0][2] * C02;

        const float n2 = P[0][0]*P[0][0] + P[0][1]*P[0][1] + P[0][2]*P[0][2]
                       + P[1][0]*P[1][0] + P[1][1]*P[1][1] + P[1][2]*P[1][2]
                       + P[2][0]*P[2][0] + P[2][1]*P[2][1] + P[2][2]*P[2][2];
        const float a2 = C00*C00 + C01*C01 + C02*C02
                       + C10*C10 + C11*C11 + C12*C12
                       + C20*C20 + C21*C21 + C22*C22;

        const float ad = fmaxf(fabsf(det), 1e-30f);
        // cond_est = sqrt(n2*a2)/ad > 1e4  <=>  n2*a2 > 1e8*ad^2 (no sqrt)
        if (it == 0) need64 = (n2 * a2 > 1e8f * ad * ad);

        const float t  = fmaxf(__builtin_amdgcn_sqrtf(a2 * __builtin_amdgcn_rcpf(n2)), 1e-20f);
        const float sg = (det < 0.0f) ? -1.0f : 1.0f;
        const float rt = __builtin_amdgcn_rsqf(t * ad);   // 1/sqrt(t*ad)
        const float c1 = 0.5f * t * rt;                   // 0.5*sqrt(t/ad)
        const float c2 = 0.5f * sg * rt;

        P[0][0] = c1 * P[0][0] + c2 * C00;  P[0][1] = c1 * P[0][1] + c2 * C01;  P[0][2] = c1 * P[0][2] + c2 * C02;
        P[1][0] = c1 * P[1][0] + c2 * C10;  P[1][1] = c1 * P[1][1] + c2 * C11;  P[1][2] = c1 * P[1][2] + c2 * C12;
        P[2][0] = c1 * P[2][0] + c2 * C20;  P[2][1] = c1 * P[2][1] + c2 * C21;  P[2][2] = c1 * P[2][2] + c2 * C22;
    }

    // ---------------- A = R^T * M * R (fp32 fast path) ----------------
    const float M3[3][3] = {{m[0], m[1], m[3]},
                            {m[1], m[2], m[4]},
                            {m[3], m[4], m[5]}};
    float T[3][3];
#pragma unroll
    for (int i = 0; i < 3; ++i)
#pragma unroll
        for (int j = 0; j < 3; ++j)
            T[i][j] = P[0][i] * M3[0][j] + P[1][i] * M3[1][j] + P[2][i] * M3[2][j];

    float A[3][3];
#pragma unroll
    for (int i = 0; i < 3; ++i)
#pragma unroll
        for (int j = 0; j < 3; ++j)
            A[i][j] = T[i][0] * P[0][j] + T[i][1] * P[1][j] + T[i][2] * P[2][j];

    // ---------------- emit lower-tri (B,6,H,W,D) fp32 ----------------
    float* ob = out + (size_t)b * 6 * NVOX;
    ob[0 * NVOX + r] = A[0][0];
    ob[1 * NVOX + r] = A[1][0];
    ob[2 * NVOX + r] = A[1][1];
    ob[3 * NVOX + r] = A[2][0];
    ob[4 * NVOX + r] = A[2][1];
    ob[5 * NVOX + r] = A[2][2];

    // -------- inline fp64 rescue (~50 of 524288 threads, cond(J)>1e4) ------
    // State in the wave's LDS slot; flagged lanes serialized via ballot+ffs.
    // No scratch (R4/R11 killer), no extra VGPR pressure (92-VGPR killer),
    // no workspace (dirty-penalty).
    const unsigned long long bm = __ballot(need64);
    if (__builtin_expect(bm != 0ull, 0)) {
        const int wv = threadIdx.x >> 6;          // wave id in block
        const int lane = threadIdx.x & 63;
        double* X = sX[wv];
        double* C = sC[wv];
        unsigned long long mm = bm;
        while (mm) {
            const int l = __ffsll(mm) - 1;
            mm &= mm - 1;
            if (lane == l) {
                // fp64 Jacobian (reload ddf neighbors)
                for (int i = 0; i < 3; ++i) {
                    const float* u = db + i * NVOX;
                    X[i*3+0] = ((double)u[(xp*64+y)*64+z] - (double)u[(xm*64+y)*64+z])
                             * (double)sx + (i == 0 ? 1.0 : 0.0);
                    X[i*3+1] = ((double)u[(x*64+yp)*64+z] - (double)u[(x*64+ym)*64+z])
                             * (double)sy + (i == 1 ? 1.0 : 0.0);
                    X[i*3+2] = ((double)u[(x*64+y)*64+zp] - (double)u[(x*64+y)*64+zm])
                             * (double)sz + (i == 2 ? 1.0 : 0.0);
                }

                // 14-iter normalized scaled-Newton polar (overflow-proof)
                for (int it = 0; it < 14; ++it) {
                    double mx = 0.0;
                    for (int k = 0; k < 9; ++k) mx = fmax(mx, fabs(X[k]));
                    const double s = 1.0 / fmax(mx, 1e-300);
                    for (int k = 0; k < 9; ++k) X[k] *= s;

                    C[0] = X[4]*X[8] - X[5]*X[7];
                    C[1] = X[5]*X[6] - X[3]*X[8];
                    C[2] = X[3]*X[7] - X[4]*X[6];
                    C[3] = X[2]*X[7] - X[1]*X[8];
                    C[4] = X[0]*X[8] - X[2]*X[6];
                    C[5] = X[1]*X[6] - X[0]*X[7];
                    C[6] = X[1]*X[5] - X[2]*X[4];
                    C[7] = X[2]*X[3] - X[0]*X[5];
                    C[8] = X[0]*X[4] - X[1]*X[3];
                    const double det = X[0]*C[0] + X[1]*C[1] + X[2]*C[2];
                    double n2d = 0.0, a2d = 0.0;
                    for (int k = 0; k < 9; ++k) { n2d += X[k]*X[k]; a2d += C[k]*C[k]; }
                    const double t  = fmax(sqrt(a2d / n2d), 1e-150);
                    const double ad = fmax(fabs(det), 1e-280);
                    const double sg = (det < 0.0) ? -1.0 : 1.0;
                    const double c1 = 0.5 * sqrt(t / ad);
                    const double c2 = 0.5 * sg / sqrt(t * ad);
                    for (int k = 0; k < 9; ++k) X[k] = c1 * X[k] + c2 * C[k];
                }

                // A = X^T * M * X  (X is now R; reuse fp32 m[] — M well-cond.)
                const double M0 = m[0], M1 = m[1], M2 = m[2];
                const double M3d = m[3], M4 = m[4], M5 = m[5];
                double Td[9];
#pragma unroll
                for (int i = 0; i < 3; ++i) {
                    Td[i*3+0] = X[0+i]*M0 + X[3+i]*M1 + X[6+i]*M3d;
                    Td[i*3+1] = X[0+i]*M1 + X[3+i]*M2 + X[6+i]*M4;
                    Td[i*3+2] = X[0+i]*M3d + X[3+i]*M4 + X[6+i]*M5;
                }

                ob[0 * NVOX + r] = (float)(Td[0]*X[0] + Td[1]*X[3] + Td[2]*X[6]);  // A00
                ob[1 * NVOX + r] = (float)(Td[3]*X[0] + Td[4]*X[3] + Td[5]*X[6]);  // A10
                ob[2 * NVOX + r] = (float)(Td[3]*X[1] + Td[4]*X[4] + Td[5]*X[7]);  // A11
                ob[3 * NVOX + r] = (float)(Td[6]*X[0] + Td[7]*X[3] + Td[8]*X[6]);  // A20
                ob[4 * NVOX + r] = (float)(Td[6]*X[1] + Td[7]*X[4] + Td[8]*X[7]);  // A21
                ob[5 * NVOX + r] = (float)(Td[6]*X[2] + Td[7]*X[5] + Td[8]*X[8]);  // A22
            }
        }
    }
}

extern "C" void kernel_launch(void* const* d_in, const int* in_sizes, int n_in,
                              void* d_out, int out_size, void* d_ws, size_t ws_size,
                              hipStream_t stream) {
    const float* dti = (const float*)d_in[0];
    const float* ddf = (const float*)d_in[1];
    float* out = (float*)d_out;
    (void)d_ws; (void)ws_size;   // NEVER touch d_ws: dirtying it costs ~5 us

    warp_fused<<<TOTAL / 256, 256, 0, stream>>>(dti, ddf, out);
}